// Round 2
// baseline (692.057 us; speedup 1.0000x reference)
//
#include <hip/hip_runtime.h>

// ---------------- problem constants ----------------
#define N_NODES 10000
#define N_EDGES 320000
#define DD      128      // node feature dim
#define EDF     64       // edge feature dim
#define EH      256
#define EO      128
#define NH      256
#define NO      128
#define LN_EPS  1e-5f
#define NODE_OUT_SZ (N_NODES * NO)   // 1,280,000 floats; agg lives here first

// cat = [src(128) | tgt(128) | diff(128) | radial(1) | dist(1) | ef(64)] = 450, pad to 480
#define AK      480
#define ASTR    488      // LDS row stride (bank-conflict-free for b128 reads)
#define HSTR    264      // h buffer stride
#define BSTR    40       // weight-chunk LDS row stride

typedef short s16x8 __attribute__((ext_vector_type(8)));
typedef float f32x4 __attribute__((ext_vector_type(4)));

__device__ __forceinline__ unsigned short f2bf(float f) {
  unsigned int u = __float_as_uint(f);
  u += 0x7FFFu + ((u >> 16) & 1u);     // RNE
  return (unsigned short)(u >> 16);
}
__device__ __forceinline__ float gelu_f(float x) {
  return 0.5f * x * (1.0f + erff(x * 0.70710678118654752440f));
}

// ---------------- ws layout (ushort elements) ----------------
#define OFF_EW1T 0          // [256 cols][480 k]
#define OFF_EW2T 122880     // [128][256]
#define OFF_NW1T 155648     // [256][256]
#define OFF_NW2T 221184     // [128][256]
#define PREP_TOT 253952

__global__ __launch_bounds__(256) void prep_weights(
    const float* __restrict__ eW1, const float* __restrict__ eW2,
    const float* __restrict__ nW1, const float* __restrict__ nW2,
    unsigned short* __restrict__ ws)
{
  int i = blockIdx.x * 256 + threadIdx.x;
  if (i < 122880) {                       // eW1t[c][k], zero radial/dist rows + K pad
    int c = i / AK, k = i - c * AK;
    float v = 0.f;
    if (k < 450 && k != 384 && k != 385) v = eW1[k * EH + c];
    ws[OFF_EW1T + i] = f2bf(v);
  } else if (i < 155648) {                // eW2t[c][k]
    int j = i - OFF_EW2T; int c = j >> 8, k = j & 255;
    ws[i] = f2bf(eW2[k * EO + c]);
  } else if (i < 221184) {                // nW1t[c][k]
    int j = i - OFF_NW1T; int c = j >> 8, k = j & 255;
    ws[i] = f2bf(nW1[k * NH + c]);
  } else if (i < PREP_TOT) {              // nW2t[c][k]
    int j = i - OFF_NW2T; int c = j >> 8, k = j & 255;
    ws[i] = f2bf(nW2[k * NO + c]);
  }
}

// ---------------- edge kernel: 32 edges/block, 4 waves ----------------
__global__ __launch_bounds__(256) void edge_kernel(
    const float* __restrict__ nf, const float* __restrict__ ef,
    const int* __restrict__ ei,
    const float* __restrict__ eW1, const float* __restrict__ eb1,
    const float* __restrict__ eg1, const float* __restrict__ ebt1,
    const float* __restrict__ eb2, const float* __restrict__ eg2,
    const float* __restrict__ ebt2,
    const unsigned short* __restrict__ W1t,   // [256][480] bf16 bits
    const unsigned short* __restrict__ W2t,   // [128][256]
    float* __restrict__ out)                  // agg at base, edge_out at +NODE_OUT_SZ
{
  __shared__ __align__(16) unsigned short Ab[32][ASTR];   // cat, later reused as h
  __shared__ __align__(16) unsigned short Bb[256][BSTR];  // weight chunk
  __shared__ float radL[32], distL[32];
  __shared__ int   tgtL[32];
  __shared__ float sumL[2][32], sqL[2][32];

  const int tid = threadIdx.x;
  const int e0  = blockIdx.x * 32;

  // ---- build A = cat (bf16), radial/dist in fp32 ----
  {
    const int r = tid >> 3, g = tid & 7;        // 8 threads per edge
    const int e = e0 + r;
    const int si = ei[e];
    const int ti = ei[N_EDGES + e];
    const float4* sp = (const float4*)(nf + (size_t)si * DD);
    const float4* tp = (const float4*)(nf + (size_t)ti * DD);
    float rad = 0.f;
#pragma unroll
    for (int q = 0; q < 4; ++q) {
      float4 s = sp[g * 4 + q];
      float4 t = tp[g * 4 + q];
      float d0 = s.x - t.x, d1 = s.y - t.y, d2 = s.z - t.z, d3 = s.w - t.w;
      rad += d0*d0 + d1*d1 + d2*d2 + d3*d3;
      int k0 = g * 16 + q * 4;
      Ab[r][k0+0] = f2bf(s.x); Ab[r][k0+1] = f2bf(s.y);
      Ab[r][k0+2] = f2bf(s.z); Ab[r][k0+3] = f2bf(s.w);
      Ab[r][128+k0+0] = f2bf(t.x); Ab[r][128+k0+1] = f2bf(t.y);
      Ab[r][128+k0+2] = f2bf(t.z); Ab[r][128+k0+3] = f2bf(t.w);
      Ab[r][256+k0+0] = f2bf(d0); Ab[r][256+k0+1] = f2bf(d1);
      Ab[r][256+k0+2] = f2bf(d2); Ab[r][256+k0+3] = f2bf(d3);
    }
    rad += __shfl_xor(rad, 1);
    rad += __shfl_xor(rad, 2);
    rad += __shfl_xor(rad, 4);
    if (g == 0) {
      radL[r]  = rad;
      distL[r] = sqrtf(rad + 1e-8f);
      tgtL[r]  = ti;
      Ab[r][384] = 0; Ab[r][385] = 0;   // handled by fp32 correction
    }
    const float4* ep = (const float4*)(ef + (size_t)e * EDF);
    float4 u = ep[g * 2], v = ep[g * 2 + 1];
    int k0 = 386 + g * 8;
    Ab[r][k0+0]=f2bf(u.x); Ab[r][k0+1]=f2bf(u.y); Ab[r][k0+2]=f2bf(u.z); Ab[r][k0+3]=f2bf(u.w);
    Ab[r][k0+4]=f2bf(v.x); Ab[r][k0+5]=f2bf(v.y); Ab[r][k0+6]=f2bf(v.z); Ab[r][k0+7]=f2bf(v.w);
    for (int k = 450 + g; k < ASTR; k += 8) Ab[r][k] = 0;   // K pad
  }

  const int lane = tid & 63, wave = tid >> 6;
  const int wr = wave >> 1, wc = wave & 1;
  const int r4 = lane >> 4, cl = lane & 15;

  f32x4 acc[8];
#pragma unroll
  for (int t = 0; t < 8; ++t) { f32x4 z = {0.f,0.f,0.f,0.f}; acc[t] = z; }

  __syncthreads();

  // ---- GEMM1: [32,480] x [480,256], wave = 16 rows x 128 cols ----
  for (int kc = 0; kc < 15; ++kc) {
    {
      const uint4* s = (const uint4*)(W1t + (size_t)tid * AK + kc * 32);
      uint4* d = (uint4*)(&Bb[tid][0]);
      d[0] = s[0]; d[1] = s[1]; d[2] = s[2]; d[3] = s[3];
    }
    __syncthreads();
    s16x8 af = *(const s16x8*)(&Ab[wr*16 + cl][kc*32 + r4*8]);
#pragma unroll
    for (int t = 0; t < 8; ++t) {
      s16x8 bf = *(const s16x8*)(&Bb[wc*128 + t*16 + cl][r4*8]);
      acc[t] = __builtin_amdgcn_mfma_f32_16x16x32_bf16(af, bf, acc[t], 0, 0, 0);
    }
    __syncthreads();
  }

  // ---- epilogue 1: bias + radial/dist fp32 correction + LN + GELU -> h ----
  float eb1c[8], eg1c[8], ebt1c[8], w4c[8], w5c[8];
#pragma unroll
  for (int t = 0; t < 8; ++t) {
    int c = wc*128 + t*16 + cl;
    eb1c[t] = eb1[c]; eg1c[t] = eg1[c]; ebt1c[t] = ebt1[c];
    w4c[t] = eW1[384*EH + c]; w5c[t] = eW1[385*EH + c];
  }
  float xs[8][4], mean1[4], inv1[4];
#pragma unroll
  for (int rr = 0; rr < 4; ++rr) {
    int row = wr*16 + r4*4 + rr;
    float rad = radL[row], dst = distL[row];
    float ps = 0.f, pq = 0.f;
#pragma unroll
    for (int t = 0; t < 8; ++t) {
      float x = acc[t][rr] + eb1c[t] + rad * w4c[t] + dst * w5c[t];
      xs[t][rr] = x; ps += x; pq += x * x;
    }
    ps += __shfl_xor(ps, 1); pq += __shfl_xor(pq, 1);
    ps += __shfl_xor(ps, 2); pq += __shfl_xor(pq, 2);
    ps += __shfl_xor(ps, 4); pq += __shfl_xor(pq, 4);
    ps += __shfl_xor(ps, 8); pq += __shfl_xor(pq, 8);
    if (cl == 0) { sumL[wc][row] = ps; sqL[wc][row] = pq; }
  }
  __syncthreads();
  unsigned short* hb = &Ab[0][0];   // reuse A region: h[32][HSTR]
#pragma unroll
  for (int rr = 0; rr < 4; ++rr) {
    int row = wr*16 + r4*4 + rr;
    float s = sumL[0][row] + sumL[1][row];
    float q = sqL[0][row] + sqL[1][row];
    float m = s * (1.f/256.f);
    float v = q * (1.f/256.f) - m * m;
    mean1[rr] = m; inv1[rr] = rsqrtf(v + LN_EPS);
  }
#pragma unroll
  for (int t = 0; t < 8; ++t) {
#pragma unroll
    for (int rr = 0; rr < 4; ++rr) {
      int row = wr*16 + r4*4 + rr;
      int c = wc*128 + t*16 + cl;
      float y = (xs[t][rr] - mean1[rr]) * inv1[rr] * eg1c[t] + ebt1c[t];
      hb[row*HSTR + c] = f2bf(gelu_f(y));
    }
  }
  __syncthreads();

  // ---- GEMM2: [32,256] x [256,128], wave = 16 rows x 64 cols ----
  f32x4 a2[4];
#pragma unroll
  for (int t = 0; t < 4; ++t) { f32x4 z = {0.f,0.f,0.f,0.f}; a2[t] = z; }

  for (int kc = 0; kc < 8; ++kc) {
    {
      int c = tid >> 1, hh = tid & 1;
      const uint4* s = (const uint4*)(W2t + (size_t)c * 256 + kc * 32 + hh * 16);
      uint4* d = (uint4*)(&Bb[c][hh * 16]);
      d[0] = s[0]; d[1] = s[1];
    }
    __syncthreads();
    s16x8 af = *(const s16x8*)(hb + (wr*16 + cl) * HSTR + kc*32 + r4*8);
#pragma unroll
    for (int t = 0; t < 4; ++t) {
      s16x8 bf = *(const s16x8*)(&Bb[wc*64 + t*16 + cl][r4*8]);
      a2[t] = __builtin_amdgcn_mfma_f32_16x16x32_bf16(af, bf, a2[t], 0, 0, 0);
    }
    __syncthreads();
  }

  // ---- epilogue 2: bias + LN + GELU -> write edge_out + scatter agg ----
  float eb2c[4], eg2c[4], ebt2c[4];
#pragma unroll
  for (int t = 0; t < 4; ++t) {
    int c = wc*64 + t*16 + cl;
    eb2c[t] = eb2[c]; eg2c[t] = eg2[c]; ebt2c[t] = ebt2[c];
  }
  float xs2[4][4], mean2[4], inv2[4];
#pragma unroll
  for (int rr = 0; rr < 4; ++rr) {
    int row = wr*16 + r4*4 + rr;
    float ps = 0.f, pq = 0.f;
#pragma unroll
    for (int t = 0; t < 4; ++t) {
      float x = a2[t][rr] + eb2c[t];
      xs2[t][rr] = x; ps += x; pq += x * x;
    }
    ps += __shfl_xor(ps, 1); pq += __shfl_xor(pq, 1);
    ps += __shfl_xor(ps, 2); pq += __shfl_xor(pq, 2);
    ps += __shfl_xor(ps, 4); pq += __shfl_xor(pq, 4);
    ps += __shfl_xor(ps, 8); pq += __shfl_xor(pq, 8);
    if (cl == 0) { sumL[wc][row] = ps; sqL[wc][row] = pq; }
  }
  __syncthreads();
#pragma unroll
  for (int rr = 0; rr < 4; ++rr) {
    int row = wr*16 + r4*4 + rr;
    float s = sumL[0][row] + sumL[1][row];
    float q = sqL[0][row] + sqL[1][row];
    float m = s * (1.f/128.f);
    float v = q * (1.f/128.f) - m * m;
    mean2[rr] = m; inv2[rr] = rsqrtf(v + LN_EPS);
  }
#pragma unroll
  for (int t = 0; t < 4; ++t) {
#pragma unroll
    for (int rr = 0; rr < 4; ++rr) {
      int row = wr*16 + r4*4 + rr;
      int c = wc*64 + t*16 + cl;
      float y = (xs2[t][rr] - mean2[rr]) * inv2[rr] * eg2c[t] + ebt2c[t];
      float val = gelu_f(y);
      int e = e0 + row;
      out[NODE_OUT_SZ + (size_t)e * EO + c] = val;
      atomicAdd(out + (size_t)tgtL[row] * NO + c, val);
    }
  }
}

// ---------------- node kernel: 32 nodes/block ----------------
__global__ __launch_bounds__(256) void node_kernel(
    const float* __restrict__ nf,
    const float* __restrict__ nb1, const float* __restrict__ ng1, const float* __restrict__ nbt1,
    const float* __restrict__ nb2, const float* __restrict__ ng2, const float* __restrict__ nbt2,
    const unsigned short* __restrict__ W1t,   // [256][256]
    const unsigned short* __restrict__ W2t,   // [128][256]
    float* __restrict__ out)                  // reads agg rows, overwrites with node_out
{
  __shared__ __align__(16) unsigned short Ab[32][HSTR];
  __shared__ __align__(16) unsigned short Bb[256][BSTR];
  __shared__ float sumL[2][32], sqL[2][32];

  const int tid = threadIdx.x;
  const int n0  = blockIdx.x * 32;

  // ---- build A = [nf | agg] ----
  {
    const int r = tid >> 3, g = tid & 7;
    const int node = n0 + r;
    if (node < N_NODES) {
      const float4* xp = (const float4*)(nf  + (size_t)node * DD);
      const float4* ap = (const float4*)(out + (size_t)node * NO);
#pragma unroll
      for (int q = 0; q < 4; ++q) {
        float4 x = xp[g*4 + q]; float4 a = ap[g*4 + q];
        int k0 = g*16 + q*4;
        Ab[r][k0+0]=f2bf(x.x); Ab[r][k0+1]=f2bf(x.y); Ab[r][k0+2]=f2bf(x.z); Ab[r][k0+3]=f2bf(x.w);
        Ab[r][128+k0+0]=f2bf(a.x); Ab[r][128+k0+1]=f2bf(a.y);
        Ab[r][128+k0+2]=f2bf(a.z); Ab[r][128+k0+3]=f2bf(a.w);
      }
    } else {
#pragma unroll
      for (int q = 0; q < 4; ++q) {
        int k0 = g*16 + q*4;
#pragma unroll
        for (int j = 0; j < 4; ++j) { Ab[r][k0+j] = 0; Ab[r][128+k0+j] = 0; }
      }
    }
  }

  const int lane = tid & 63, wave = tid >> 6;
  const int wr = wave >> 1, wc = wave & 1;
  const int r4 = lane >> 4, cl = lane & 15;

  f32x4 acc[8];
#pragma unroll
  for (int t = 0; t < 8; ++t) { f32x4 z = {0.f,0.f,0.f,0.f}; acc[t] = z; }

  __syncthreads();

  // ---- GEMM1: [32,256] x [256,256] ----
  for (int kc = 0; kc < 8; ++kc) {
    {
      const uint4* s = (const uint4*)(W1t + (size_t)tid * 256 + kc * 32);
      uint4* d = (uint4*)(&Bb[tid][0]);
      d[0] = s[0]; d[1] = s[1]; d[2] = s[2]; d[3] = s[3];
    }
    __syncthreads();
    s16x8 af = *(const s16x8*)(&Ab[wr*16 + cl][kc*32 + r4*8]);
#pragma unroll
    for (int t = 0; t < 8; ++t) {
      s16x8 bf = *(const s16x8*)(&Bb[wc*128 + t*16 + cl][r4*8]);
      acc[t] = __builtin_amdgcn_mfma_f32_16x16x32_bf16(af, bf, acc[t], 0, 0, 0);
    }
    __syncthreads();
  }

  // ---- epilogue 1 ----
  float b1c[8], g1c[8], bt1c[8];
#pragma unroll
  for (int t = 0; t < 8; ++t) {
    int c = wc*128 + t*16 + cl;
    b1c[t] = nb1[c]; g1c[t] = ng1[c]; bt1c[t] = nbt1[c];
  }
  float xs[8][4], mean1[4], inv1[4];
#pragma unroll
  for (int rr = 0; rr < 4; ++rr) {
    int row = wr*16 + r4*4 + rr;
    float ps = 0.f, pq = 0.f;
#pragma unroll
    for (int t = 0; t < 8; ++t) {
      float x = acc[t][rr] + b1c[t];
      xs[t][rr] = x; ps += x; pq += x * x;
    }
    ps += __shfl_xor(ps, 1); pq += __shfl_xor(pq, 1);
    ps += __shfl_xor(ps, 2); pq += __shfl_xor(pq, 2);
    ps += __shfl_xor(ps, 4); pq += __shfl_xor(pq, 4);
    ps += __shfl_xor(ps, 8); pq += __shfl_xor(pq, 8);
    if (cl == 0) { sumL[wc][row] = ps; sqL[wc][row] = pq; }
  }
  __syncthreads();
  unsigned short* hb = &Ab[0][0];
#pragma unroll
  for (int rr = 0; rr < 4; ++rr) {
    int row = wr*16 + r4*4 + rr;
    float s = sumL[0][row] + sumL[1][row];
    float q = sqL[0][row] + sqL[1][row];
    float m = s * (1.f/256.f);
    float v = q * (1.f/256.f) - m * m;
    mean1[rr] = m; inv1[rr] = rsqrtf(v + LN_EPS);
  }
#pragma unroll
  for (int t = 0; t < 8; ++t) {
#pragma unroll
    for (int rr = 0; rr < 4; ++rr) {
      int row = wr*16 + r4*4 + rr;
      int c = wc*128 + t*16 + cl;
      float y = (xs[t][rr] - mean1[rr]) * inv1[rr] * g1c[t] + bt1c[t];
      hb[row*HSTR + c] = f2bf(gelu_f(y));
    }
  }
  __syncthreads();

  // ---- GEMM2: [32,256] x [256,128] ----
  f32x4 a2[4];
#pragma unroll
  for (int t = 0; t < 4; ++t) { f32x4 z = {0.f,0.f,0.f,0.f}; a2[t] = z; }

  for (int kc = 0; kc < 8; ++kc) {
    {
      int c = tid >> 1, hh = tid & 1;
      const uint4* s = (const uint4*)(W2t + (size_t)c * 256 + kc * 32 + hh * 16);
      uint4* d = (uint4*)(&Bb[c][hh * 16]);
      d[0] = s[0]; d[1] = s[1];
    }
    __syncthreads();
    s16x8 af = *(const s16x8*)(hb + (wr*16 + cl) * HSTR + kc*32 + r4*8);
#pragma unroll
    for (int t = 0; t < 4; ++t) {
      s16x8 bf = *(const s16x8*)(&Bb[wc*64 + t*16 + cl][r4*8]);
      a2[t] = __builtin_amdgcn_mfma_f32_16x16x32_bf16(af, bf, a2[t], 0, 0, 0);
    }
    __syncthreads();
  }

  // ---- epilogue 2 -> node_out ----
  float b2c[4], g2c[4], bt2c[4];
#pragma unroll
  for (int t = 0; t < 4; ++t) {
    int c = wc*64 + t*16 + cl;
    b2c[t] = nb2[c]; g2c[t] = ng2[c]; bt2c[t] = nbt2[c];
  }
  float xs2[4][4], mean2[4], inv2[4];
#pragma unroll
  for (int rr = 0; rr < 4; ++rr) {
    int row = wr*16 + r4*4 + rr;
    float ps = 0.f, pq = 0.f;
#pragma unroll
    for (int t = 0; t < 4; ++t) {
      float x = a2[t][rr] + b2c[t];
      xs2[t][rr] = x; ps += x; pq += x * x;
    }
    ps += __shfl_xor(ps, 1); pq += __shfl_xor(pq, 1);
    ps += __shfl_xor(ps, 2); pq += __shfl_xor(pq, 2);
    ps += __shfl_xor(ps, 4); pq += __shfl_xor(pq, 4);
    ps += __shfl_xor(ps, 8); pq += __shfl_xor(pq, 8);
    if (cl == 0) { sumL[wc][row] = ps; sqL[wc][row] = pq; }
  }
  __syncthreads();
#pragma unroll
  for (int rr = 0; rr < 4; ++rr) {
    int row = wr*16 + r4*4 + rr;
    float s = sumL[0][row] + sumL[1][row];
    float q = sqL[0][row] + sqL[1][row];
    float m = s * (1.f/128.f);
    float v = q * (1.f/128.f) - m * m;
    mean2[rr] = m; inv2[rr] = rsqrtf(v + LN_EPS);
  }
#pragma unroll
  for (int t = 0; t < 4; ++t) {
#pragma unroll
    for (int rr = 0; rr < 4; ++rr) {
      int row = wr*16 + r4*4 + rr;
      int node = n0 + row;
      if (node < N_NODES) {
        int c = wc*64 + t*16 + cl;
        float y = (xs2[t][rr] - mean2[rr]) * inv2[rr] * g2c[t] + bt2c[t];
        out[(size_t)node * NO + c] = gelu_f(y);
      }
    }
  }
}

// ---------------- launch ----------------
extern "C" void kernel_launch(void* const* d_in, const int* in_sizes, int n_in,
                              void* d_out, int out_size, void* d_ws, size_t ws_size,
                              hipStream_t stream) {
  const float* nf   = (const float*)d_in[0];
  const float* ef   = (const float*)d_in[1];
  const int*   ei   = (const int*)d_in[2];
  const float* eW1  = (const float*)d_in[3];
  const float* eb1  = (const float*)d_in[4];
  const float* eg1  = (const float*)d_in[5];
  const float* ebt1 = (const float*)d_in[6];
  const float* eW2  = (const float*)d_in[7];
  const float* eb2  = (const float*)d_in[8];
  const float* eg2  = (const float*)d_in[9];
  const float* ebt2 = (const float*)d_in[10];
  const float* nW1  = (const float*)d_in[11];
  const float* nb1  = (const float*)d_in[12];
  const float* ng1  = (const float*)d_in[13];
  const float* nbt1 = (const float*)d_in[14];
  const float* nW2  = (const float*)d_in[15];
  const float* nb2  = (const float*)d_in[16];
  const float* ng2  = (const float*)d_in[17];
  const float* nbt2 = (const float*)d_in[18];
  float* out = (float*)d_out;
  unsigned short* ws = (unsigned short*)d_ws;
  (void)eW2; (void)in_sizes; (void)n_in; (void)out_size; (void)ws_size;

  // zero agg region (node_out area of d_out)
  hipMemsetAsync(d_out, 0, (size_t)NODE_OUT_SZ * sizeof(float), stream);

  prep_weights<<<(PREP_TOT + 255) / 256, 256, 0, stream>>>(eW1, eW2, nW1, nW2, ws);

  edge_kernel<<<N_EDGES / 32, 256, 0, stream>>>(
      nf, ef, ei, eW1, eb1, eg1, ebt1, eb2, eg2, ebt2,
      ws + OFF_EW1T, ws + OFF_EW2T, out);

  node_kernel<<<(N_NODES + 31) / 32, 256, 0, stream>>>(
      nf, nb1, ng1, nbt1, nb2, ng2, nbt2,
      ws + OFF_NW1T, ws + OFF_NW2T, out);
}

// Round 4
// 523.756 us; speedup vs baseline: 1.3213x; 1.3213x over previous
//
#include <hip/hip_runtime.h>

// ---------------- problem constants ----------------
#define N_NODES 10000
#define N_EDGES 320000
#define DD      128
#define EDF     64
#define EH      256
#define EO      128
#define NH      256
#define NO      128
#define LN_EPS  1e-5f
#define NODE_OUT_SZ (N_NODES * NO)   // agg lives here first, node_out overwrites

// edge A: K = 448 = [src128|tgt128|diff128|ef64]; rad/dist handled as fp32 rank-2 epilogue fix
#define AK    448
#define NKC1  14         // GEMM1 K-chunks of 32
#define NKC2  8          // GEMM2 K-chunks of 32
#define M_E   64         // edges per block
#define HSTR  264        // h LDS stride (132 dw == 4 mod 32 -> conflict-free b128 reads)

typedef short s16x8 __attribute__((ext_vector_type(8)));
typedef float f32x4 __attribute__((ext_vector_type(4)));

__device__ __forceinline__ unsigned short f2bf(float f) {
  unsigned int u = __float_as_uint(f);
  u += 0x7FFFu + ((u >> 16) & 1u);     // RNE
  return (unsigned short)(u >> 16);
}
__device__ __forceinline__ unsigned int pk2(float a, float b) {
  return (unsigned int)f2bf(a) | ((unsigned int)f2bf(b) << 16);
}
__device__ __forceinline__ uint4 pk8(float4 a, float4 b) {
  return make_uint4(pk2(a.x,a.y), pk2(a.z,a.w), pk2(b.x,b.y), pk2(b.z,b.w));
}
// fast GELU: x * sigmoid(1.5957691(x + 0.044715 x^3)); |err| <= ~1e-3 vs exact erf form
__device__ __forceinline__ float gelu_f(float x) {
  float x2 = x * x;
  float p  = __builtin_fmaf(0.044715f * x2, x, x);
  float e  = __expf(-1.5957691216057308f * p);
  return x * __builtin_amdgcn_rcpf(1.0f + e);
}

typedef const __attribute__((address_space(1))) void GV;
typedef __attribute__((address_space(3))) void LV;
__device__ __forceinline__ void gload16(const void* g, void* l) {
  __builtin_amdgcn_global_load_lds((GV*)g, (LV*)l, 16, 0, 0);
}

// ---------------- ws layout (ushort elements) ----------------
#define OFF_EW1 0          // [14 kc][4 kq][256 col][8 j] = 114688
#define OFF_EW2 114688     // [8 kc][4 kq][128 col][8 j]  = 32768
#define OFF_NW1 147456     // [256 c][256 k]              = 65536
#define OFF_NW2 212992     // [128 c][256 k]              = 32768
#define PREP_TOT 245760

__global__ __launch_bounds__(256) void prep_weights(
    const float* __restrict__ eW1, const float* __restrict__ eW2,
    const float* __restrict__ nW1, const float* __restrict__ nW2,
    unsigned short* __restrict__ ws)
{
  int i = blockIdx.x * 256 + threadIdx.x;
  if (i < OFF_EW2) {                       // eW1 -> [kc][kq][col][8]
    int kc = i >> 13, rem = i & 8191;
    int kq = rem >> 11, rem2 = rem & 2047;
    int col = rem2 >> 3, j = rem2 & 7;
    int k = kc * 32 + kq * 8 + j;          // 0..447 in A-space
    int kw = (k < 384) ? k : k + 2;        // skip rad/dist rows of eW1
    ws[i] = f2bf(eW1[kw * EH + col]);
  } else if (i < OFF_NW1) {                // eW2 -> [kc][kq][col][8]
    int j0 = i - OFF_EW2;
    int kc = j0 >> 12, rem = j0 & 4095;
    int kq = rem >> 10, col = (rem >> 3) & 127, j = rem & 7;
    int k = kc * 32 + kq * 8 + j;
    ws[i] = f2bf(eW2[k * EO + col]);
  } else if (i < OFF_NW2) {                // nW1t[c][k]
    int j0 = i - OFF_NW1; int c = j0 >> 8, k = j0 & 255;
    ws[i] = f2bf(nW1[k * NH + c]);
  } else if (i < PREP_TOT) {               // nW2t[c][k]
    int j0 = i - OFF_NW2; int c = j0 >> 8, k = j0 & 255;
    ws[i] = f2bf(nW2[k * NO + c]);
  }
}

// ---------------- edge kernel: 64 edges/block, 8 waves ----------------
__global__ __launch_bounds__(512, 4) void edge_kernel(
    const float* __restrict__ nf, const float* __restrict__ ef,
    const int* __restrict__ ei,
    const float* __restrict__ eW1, const float* __restrict__ eb1,
    const float* __restrict__ eg1, const float* __restrict__ ebt1,
    const float* __restrict__ eb2, const float* __restrict__ eg2,
    const float* __restrict__ ebt2,
    const unsigned short* __restrict__ W1e,   // [14][4][256][8]
    const unsigned short* __restrict__ W2e,   // [8][4][128][8]
    float* __restrict__ out)
{
  // A: 64 rows x 448 bf16, XOR-swizzled in 16B units within 128B windows. 57344 B.
  // Reused after GEMM1 as h[64][HSTR] (33792 B).
  __shared__ __align__(16) unsigned short Ab[M_E * AK];
  __shared__ __align__(16) unsigned short Bb[8192];    // 16 KB staging (linear for global_load_lds)
  __shared__ float radL[M_E], distL[M_E];
  __shared__ int   tgtL[M_E];
  __shared__ float sumL[2][M_E], sqL[2][M_E];

  const int tid  = threadIdx.x;
  const int lane = tid & 63;
  const int wave = tid >> 6;            // 0..7
  const int e0   = blockIdx.x * M_E;

  // ---- prefetch GEMM1 chunk 0 into Bb (async, drains at first barrier) ----
  {
    const char* g = (const char*)W1e + wave * 2048 + lane * 16;
    char* l = (char*)Bb + wave * 2048;
    gload16(g, l);
    gload16(g + 1024, l + 1024);
  }

  // ---- build A (bf16, swizzled, vectorized b128 writes) ----
  {
    const int r = tid >> 3, g = tid & 7;   // 8 threads per edge
    const int e = e0 + r;
    const int si = ei[e];
    const int ti = ei[N_EDGES + e];
    const float4* sp = (const float4*)(nf + (size_t)si * DD) + g * 4;
    const float4* tp = (const float4*)(nf + (size_t)ti * DD) + g * 4;
    float4 s0 = sp[0], s1 = sp[1], s2 = sp[2], s3 = sp[3];
    float4 t0 = tp[0], t1 = tp[1], t2 = tp[2], t3 = tp[3];
    float4 d0, d1, d2, d3;
    d0.x=s0.x-t0.x; d0.y=s0.y-t0.y; d0.z=s0.z-t0.z; d0.w=s0.w-t0.w;
    d1.x=s1.x-t1.x; d1.y=s1.y-t1.y; d1.z=s1.z-t1.z; d1.w=s1.w-t1.w;
    d2.x=s2.x-t2.x; d2.y=s2.y-t2.y; d2.z=s2.z-t2.z; d2.w=s2.w-t2.w;
    d3.x=s3.x-t3.x; d3.y=s3.y-t3.y; d3.z=s3.z-t3.z; d3.w=s3.w-t3.w;
    float rad = d0.x*d0.x + d0.y*d0.y + d0.z*d0.z + d0.w*d0.w
              + d1.x*d1.x + d1.y*d1.y + d1.z*d1.z + d1.w*d1.w
              + d2.x*d2.x + d2.y*d2.y + d2.z*d2.z + d2.w*d2.w
              + d3.x*d3.x + d3.y*d3.y + d3.z*d3.z + d3.w*d3.w;
    const int rx = r & 7;
    char* Arow = (char*)Ab + r * (AK * 2);
    // unit u -> phys (u&~7) | ((u&7)^rx)
    #define STA(u, v) *(uint4*)(Arow + (((u) & ~7) | (((u) & 7) ^ rx)) * 16) = (v)
    STA(2*g,      pk8(s0, s1));  STA(2*g + 1,  pk8(s2, s3));
    STA(16 + 2*g, pk8(t0, t1));  STA(17 + 2*g, pk8(t2, t3));
    STA(32 + 2*g, pk8(d0, d1));  STA(33 + 2*g, pk8(d2, d3));
    const float4* ep = (const float4*)(ef + (size_t)e * EDF) + g * 2;
    float4 u0 = ep[0], u1 = ep[1];
    STA(48 + g,   pk8(u0, u1));
    #undef STA
    rad += __shfl_xor(rad, 1);
    rad += __shfl_xor(rad, 2);
    rad += __shfl_xor(rad, 4);
    if (g == 0) {
      radL[r]  = rad;
      distL[r] = sqrtf(rad + 1e-8f);
      tgtL[r]  = ti;
    }
  }

  const int wr = wave >> 1, wc = wave & 1;    // 4 row-groups x 2 col-groups
  const int r4 = lane >> 4, cl = lane & 15;
  const int arow = wr * 16 + cl;
  const int rx = arow & 7;
  const char* Abase = (const char*)Ab + arow * (AK * 2);

  f32x4 acc[8];
#pragma unroll
  for (int t = 0; t < 8; ++t) { f32x4 z = {0.f,0.f,0.f,0.f}; acc[t] = z; }

  __syncthreads();   // A ready; chunk-0 staged (vmcnt drained at barrier)

  // ---- GEMM1: [64,448] x [448,256]; wave tile 16 rows x 128 cols ----
  for (int kc = 0; ; ) {
    int u = kc * 4 + r4;
    int pu = (u & ~7) | ((u & 7) ^ rx);
    s16x8 af = *(const s16x8*)(Abase + pu * 16);
#pragma unroll
    for (int t = 0; t < 8; ++t) {
      s16x8 bf = *(const s16x8*)((const char*)Bb + r4 * 4096 + (wc * 128 + t * 16 + cl) * 16);
      acc[t] = __builtin_amdgcn_mfma_f32_16x16x32_bf16(af, bf, acc[t], 0, 0, 0);
    }
    if (++kc == NKC1) break;
    __syncthreads();           // all waves done reading Bb
    {
      const char* g = (const char*)W1e + kc * 16384 + wave * 2048 + lane * 16;
      char* l = (char*)Bb + wave * 2048;
      gload16(g, l);
      gload16(g + 1024, l + 1024);
    }
    __syncthreads();           // staged
  }

  // ---- epilogue 1: bias + fp32 rad/dist correction + LN + GELU -> h ----
  float eb1c[8], eg1c[8], ebt1c[8], w4c[8], w5c[8];
#pragma unroll
  for (int t = 0; t < 8; ++t) {
    int c = wc * 128 + t * 16 + cl;
    eb1c[t] = eb1[c]; eg1c[t] = eg1[c]; ebt1c[t] = ebt1[c];
    w4c[t] = eW1[384 * EH + c]; w5c[t] = eW1[385 * EH + c];
  }
  float xs[8][4], mean1[4], inv1[4];
#pragma unroll
  for (int rr = 0; rr < 4; ++rr) {
    int row = wr * 16 + r4 * 4 + rr;
    float rad = radL[row], dst = distL[row];
    float ps = 0.f, pq = 0.f;
#pragma unroll
    for (int t = 0; t < 8; ++t) {
      float x = acc[t][rr] + eb1c[t] + rad * w4c[t] + dst * w5c[t];
      xs[t][rr] = x; ps += x; pq += x * x;
    }
    ps += __shfl_xor(ps, 1); pq += __shfl_xor(pq, 1);
    ps += __shfl_xor(ps, 2); pq += __shfl_xor(pq, 2);
    ps += __shfl_xor(ps, 4); pq += __shfl_xor(pq, 4);
    ps += __shfl_xor(ps, 8); pq += __shfl_xor(pq, 8);
    if (cl == 0) { sumL[wc][row] = ps; sqL[wc][row] = pq; }
  }
  __syncthreads();   // sums visible; also: all GEMM1 A/B reads complete

  // prefetch GEMM2 chunk 0 (Bb free now)
  {
    const char* g = (const char*)W2e + wave * 1024 + lane * 16;
    gload16(g, (char*)Bb + wave * 1024);
  }

  unsigned short* hb = (unsigned short*)Ab;   // h[64][HSTR] overlays A
#pragma unroll
  for (int rr = 0; rr < 4; ++rr) {
    int row = wr * 16 + r4 * 4 + rr;
    float s = sumL[0][row] + sumL[1][row];
    float q = sqL[0][row] + sqL[1][row];
    float m = s * (1.f / 256.f);
    float v = q * (1.f / 256.f) - m * m;
    mean1[rr] = m; inv1[rr] = rsqrtf(v + LN_EPS);
  }
#pragma unroll
  for (int t = 0; t < 8; ++t) {
#pragma unroll
    for (int rr = 0; rr < 4; ++rr) {
      int row = wr * 16 + r4 * 4 + rr;
      int c = wc * 128 + t * 16 + cl;
      float y = (xs[t][rr] - mean1[rr]) * inv1[rr] * eg1c[t] + ebt1c[t];
      hb[row * HSTR + c] = f2bf(gelu_f(y));
    }
  }
  __syncthreads();   // h ready + GEMM2 chunk 0 staged

  // ---- GEMM2: [64,256] x [256,128]; wave tile 16 rows x 64 cols ----
  f32x4 a2[4];
#pragma unroll
  for (int t = 0; t < 4; ++t) { f32x4 z = {0.f,0.f,0.f,0.f}; a2[t] = z; }

  for (int kc = 0; ; ) {
    s16x8 af = *(const s16x8*)((const char*)hb + arow * (HSTR * 2) + kc * 64 + r4 * 16);
#pragma unroll
    for (int t = 0; t < 4; ++t) {
      s16x8 bf = *(const s16x8*)((const char*)Bb + r4 * 2048 + (wc * 64 + t * 16 + cl) * 16);
      a2[t] = __builtin_amdgcn_mfma_f32_16x16x32_bf16(af, bf, a2[t], 0, 0, 0);
    }
    if (++kc == NKC2) break;
    __syncthreads();
    {
      const char* g = (const char*)W2e + kc * 8192 + wave * 1024 + lane * 16;
      gload16(g, (char*)Bb + wave * 1024);
    }
    __syncthreads();
  }

  // ---- epilogue 2: bias + LN + GELU -> edge_out (nt) + atomic agg ----
  float eb2c[4], eg2c[4], ebt2c[4];
#pragma unroll
  for (int t = 0; t < 4; ++t) {
    int c = wc * 64 + t * 16 + cl;
    eb2c[t] = eb2[c]; eg2c[t] = eg2[c]; ebt2c[t] = ebt2[c];
  }
  float xs2[4][4], mean2[4], inv2[4];
#pragma unroll
  for (int rr = 0; rr < 4; ++rr) {
    int row = wr * 16 + r4 * 4 + rr;
    float ps = 0.f, pq = 0.f;
#pragma unroll
    for (int t = 0; t < 4; ++t) {
      float x = a2[t][rr] + eb2c[t];
      xs2[t][rr] = x; ps += x; pq += x * x;
    }
    ps += __shfl_xor(ps, 1); pq += __shfl_xor(pq, 1);
    ps += __shfl_xor(ps, 2); pq += __shfl_xor(pq, 2);
    ps += __shfl_xor(ps, 4); pq += __shfl_xor(pq, 4);
    ps += __shfl_xor(ps, 8); pq += __shfl_xor(pq, 8);
    if (cl == 0) { sumL[wc][row] = ps; sqL[wc][row] = pq; }
  }
  __syncthreads();
#pragma unroll
  for (int rr = 0; rr < 4; ++rr) {
    int row = wr * 16 + r4 * 4 + rr;
    float s = sumL[0][row] + sumL[1][row];
    float q = sqL[0][row] + sqL[1][row];
    float m = s * (1.f / 128.f);
    float v = q * (1.f / 128.f) - m * m;
    mean2[rr] = m; inv2[rr] = rsqrtf(v + LN_EPS);
  }
#pragma unroll
  for (int t = 0; t < 4; ++t) {
#pragma unroll
    for (int rr = 0; rr < 4; ++rr) {
      int row = wr * 16 + r4 * 4 + rr;
      int c = wc * 64 + t * 16 + cl;
      float y = (xs2[t][rr] - mean2[rr]) * inv2[rr] * eg2c[t] + ebt2c[t];
      float val = gelu_f(y);
      int e = e0 + row;
      __builtin_nontemporal_store(val, out + NODE_OUT_SZ + (size_t)e * EO + c);
      atomicAdd(out + (size_t)tgtL[row] * NO + c, val);
    }
  }
}

// ---------------- node kernel: 32 nodes/block (baseline structure + fast gelu) ----------------
__global__ __launch_bounds__(256) void node_kernel(
    const float* __restrict__ nf,
    const float* __restrict__ nb1, const float* __restrict__ ng1, const float* __restrict__ nbt1,
    const float* __restrict__ nb2, const float* __restrict__ ng2, const float* __restrict__ nbt2,
    const unsigned short* __restrict__ W1t,   // [256][256]
    const unsigned short* __restrict__ W2t,   // [128][256]
    float* __restrict__ out)
{
  __shared__ __align__(16) unsigned short Ab[32][HSTR];
  __shared__ __align__(16) unsigned short Bb[256][40];
  __shared__ float sumL[2][32], sqL[2][32];

  const int tid = threadIdx.x;
  const int n0  = blockIdx.x * 32;

  {
    const int r = tid >> 3, g = tid & 7;
    const int node = n0 + r;
    if (node < N_NODES) {
      const float4* xp = (const float4*)(nf  + (size_t)node * DD);
      const float4* ap = (const float4*)(out + (size_t)node * NO);
#pragma unroll
      for (int q = 0; q < 4; ++q) {
        float4 x = xp[g*4 + q]; float4 a = ap[g*4 + q];
        int k0 = g*16 + q*4;
        Ab[r][k0+0]=f2bf(x.x); Ab[r][k0+1]=f2bf(x.y); Ab[r][k0+2]=f2bf(x.z); Ab[r][k0+3]=f2bf(x.w);
        Ab[r][128+k0+0]=f2bf(a.x); Ab[r][128+k0+1]=f2bf(a.y);
        Ab[r][128+k0+2]=f2bf(a.z); Ab[r][128+k0+3]=f2bf(a.w);
      }
    } else {
#pragma unroll
      for (int q = 0; q < 4; ++q) {
        int k0 = g*16 + q*4;
#pragma unroll
        for (int j = 0; j < 4; ++j) { Ab[r][k0+j] = 0; Ab[r][128+k0+j] = 0; }
      }
    }
  }

  const int lane = tid & 63, wave = tid >> 6;
  const int wr = wave >> 1, wc = wave & 1;
  const int r4 = lane >> 4, cl = lane & 15;

  f32x4 acc[8];
#pragma unroll
  for (int t = 0; t < 8; ++t) { f32x4 z = {0.f,0.f,0.f,0.f}; acc[t] = z; }

  __syncthreads();

  for (int kc = 0; kc < 8; ++kc) {
    {
      const uint4* s = (const uint4*)(W1t + (size_t)tid * 256 + kc * 32);
      uint4* d = (uint4*)(&Bb[tid][0]);
      d[0] = s[0]; d[1] = s[1]; d[2] = s[2]; d[3] = s[3];
    }
    __syncthreads();
    s16x8 af = *(const s16x8*)(&Ab[wr*16 + cl][kc*32 + r4*8]);
#pragma unroll
    for (int t = 0; t < 8; ++t) {
      s16x8 bf = *(const s16x8*)(&Bb[wc*128 + t*16 + cl][r4*8]);
      acc[t] = __builtin_amdgcn_mfma_f32_16x16x32_bf16(af, bf, acc[t], 0, 0, 0);
    }
    __syncthreads();
  }

  float b1c[8], g1c[8], bt1c[8];
#pragma unroll
  for (int t = 0; t < 8; ++t) {
    int c = wc*128 + t*16 + cl;
    b1c[t] = nb1[c]; g1c[t] = ng1[c]; bt1c[t] = nbt1[c];
  }
  float xs[8][4], mean1[4], inv1[4];
#pragma unroll
  for (int rr = 0; rr < 4; ++rr) {
    int row = wr*16 + r4*4 + rr;
    float ps = 0.f, pq = 0.f;
#pragma unroll
    for (int t = 0; t < 8; ++t) {
      float x = acc[t][rr] + b1c[t];
      xs[t][rr] = x; ps += x; pq += x * x;
    }
    ps += __shfl_xor(ps, 1); pq += __shfl_xor(pq, 1);
    ps += __shfl_xor(ps, 2); pq += __shfl_xor(pq, 2);
    ps += __shfl_xor(ps, 4); pq += __shfl_xor(pq, 4);
    ps += __shfl_xor(ps, 8); pq += __shfl_xor(pq, 8);
    if (cl == 0) { sumL[wc][row] = ps; sqL[wc][row] = pq; }
  }
  __syncthreads();
  unsigned short* hb = &Ab[0][0];
#pragma unroll
  for (int rr = 0; rr < 4; ++rr) {
    int row = wr*16 + r4*4 + rr;
    float s = sumL[0][row] + sumL[1][row];
    float q = sqL[0][row] + sqL[1][row];
    float m = s * (1.f/256.f);
    float v = q * (1.f/256.f) - m * m;
    mean1[rr] = m; inv1[rr] = rsqrtf(v + LN_EPS);
  }
#pragma unroll
  for (int t = 0; t < 8; ++t) {
#pragma unroll
    for (int rr = 0; rr < 4; ++rr) {
      int row = wr*16 + r4*4 + rr;
      int c = wc*128 + t*16 + cl;
      float y = (xs[t][rr] - mean1[rr]) * inv1[rr] * g1c[t] + bt1c[t];
      hb[row*HSTR + c] = f2bf(gelu_f(y));
    }
  }
  __syncthreads();

  f32x4 a2[4];
#pragma unroll
  for (int t = 0; t < 4; ++t) { f32x4 z = {0.f,0.f,0.f,0.f}; a2[t] = z; }

  for (int kc = 0; kc < 8; ++kc) {
    {
      int c = tid >> 1, hh = tid & 1;
      const uint4* s = (const uint4*)(W2t + (size_t)c * 256 + kc * 32 + hh * 16);
      uint4* d = (uint4*)(&Bb[c][hh * 16]);
      d[0] = s[0]; d[1] = s[1];
    }
    __syncthreads();
    s16x8 af = *(const s16x8*)(hb + (wr*16 + cl) * HSTR + kc*32 + r4*8);
#pragma unroll
    for (int t = 0; t < 4; ++t) {
      s16x8 bf = *(const s16x8*)(&Bb[wc*64 + t*16 + cl][r4*8]);
      a2[t] = __builtin_amdgcn_mfma_f32_16x16x32_bf16(af, bf, a2[t], 0, 0, 0);
    }
    __syncthreads();
  }

  float b2c[4], g2c[4], bt2c[4];
#pragma unroll
  for (int t = 0; t < 4; ++t) {
    int c = wc*64 + t*16 + cl;
    b2c[t] = nb2[c]; g2c[t] = ng2[c]; bt2c[t] = nbt2[c];
  }
  float xs2[4][4], mean2[4], inv2[4];
#pragma unroll
  for (int rr = 0; rr < 4; ++rr) {
    int row = wr*16 + r4*4 + rr;
    float ps = 0.f, pq = 0.f;
#pragma unroll
    for (int t = 0; t < 4; ++t) {
      float x = a2[t][rr] + b2c[t];
      xs2[t][rr] = x; ps += x; pq += x * x;
    }
    ps += __shfl_xor(ps, 1); pq += __shfl_xor(pq, 1);
    ps += __shfl_xor(ps, 2); pq += __shfl_xor(pq, 2);
    ps += __shfl_xor(ps, 4); pq += __shfl_xor(pq, 4);
    ps += __shfl_xor(ps, 8); pq += __shfl_xor(pq, 8);
    if (cl == 0) { sumL[wc][row] = ps; sqL[wc][row] = pq; }
  }
  __syncthreads();
#pragma unroll
  for (int rr = 0; rr < 4; ++rr) {
    int row = wr*16 + r4*4 + rr;
    float s = sumL[0][row] + sumL[1][row];
    float q = sqL[0][row] + sqL[1][row];
    float m = s * (1.f/128.f);
    float v = q * (1.f/128.f) - m * m;
    mean2[rr] = m; inv2[rr] = rsqrtf(v + LN_EPS);
  }
#pragma unroll
  for (int t = 0; t < 4; ++t) {
#pragma unroll
    for (int rr = 0; rr < 4; ++rr) {
      int row = wr*16 + r4*4 + rr;
      int node = n0 + row;
      if (node < N_NODES) {
        int c = wc*64 + t*16 + cl;
        float y = (xs2[t][rr] - mean2[rr]) * inv2[rr] * g2c[t] + bt2c[t];
        out[(size_t)node * NO + c] = gelu_f(y);
      }
    }
  }
}

// ---------------- launch ----------------
extern "C" void kernel_launch(void* const* d_in, const int* in_sizes, int n_in,
                              void* d_out, int out_size, void* d_ws, size_t ws_size,
                              hipStream_t stream) {
  const float* nf   = (const float*)d_in[0];
  const float* ef   = (const float*)d_in[1];
  const int*   ei   = (const int*)d_in[2];
  const float* eW1  = (const float*)d_in[3];
  const float* eb1  = (const float*)d_in[4];
  const float* eg1  = (const float*)d_in[5];
  const float* ebt1 = (const float*)d_in[6];
  const float* eW2  = (const float*)d_in[7];
  const float* eb2  = (const float*)d_in[8];
  const float* eg2  = (const float*)d_in[9];
  const float* ebt2 = (const float*)d_in[10];
  const float* nW1  = (const float*)d_in[11];
  const float* nb1  = (const float*)d_in[12];
  const float* ng1  = (const float*)d_in[13];
  const float* nbt1 = (const float*)d_in[14];
  const float* nW2  = (const float*)d_in[15];
  const float* nb2  = (const float*)d_in[16];
  const float* ng2  = (const float*)d_in[17];
  const float* nbt2 = (const float*)d_in[18];
  float* out = (float*)d_out;
  unsigned short* ws = (unsigned short*)d_ws;
  (void)in_sizes; (void)n_in; (void)out_size; (void)ws_size;

  hipMemsetAsync(d_out, 0, (size_t)NODE_OUT_SZ * sizeof(float), stream);

  prep_weights<<<PREP_TOT / 256, 256, 0, stream>>>(eW1, eW2, nW1, nW2, ws);

  edge_kernel<<<N_EDGES / M_E, 512, 0, stream>>>(
      nf, ef, ei, eW1, eb1, eg1, ebt1, eb2, eg2, ebt2,
      ws + OFF_EW1, ws + OFF_EW2, out);

  node_kernel<<<(N_NODES + 31) / 32, 256, 0, stream>>>(
      nf, nb1, ng1, nbt1, nb2, ng2, nbt2,
      ws + OFF_NW1, ws + OFF_NW2, out);
}

// Round 6
// 515.451 us; speedup vs baseline: 1.3426x; 1.0161x over previous
//
#include <hip/hip_runtime.h>

// ---------------- problem constants ----------------
#define N_NODES 10000
#define N_EDGES 320000
#define DD      128
#define EDF     64
#define EH      256
#define EO      128
#define NH      256
#define NO      128
#define LN_EPS  1e-5f
#define NODE_OUT_SZ (N_NODES * NO)   // agg lives here first, node_out overwrites

// edge A: K = 320 = [src128|tgt128|ef64] with diff FOLDED into src/tgt weights:
//   cat@W = src(Ws+Wd) + tgt(Wt-Wd) + ef*Wef + radial*w384 + dist*w385 (fp32 epilogue fix)
#define AK      320
#define NKC1    10       // edge GEMM1 K-chunks of 32
#define NKC2    8        // edge GEMM2 K-chunks of 32
#define ME_TILE 64       // edges per block
#define HSTR    264      // edge h LDS stride (132 dw == 4 mod 32 -> conflict-free b128 reads)

typedef short s16x8 __attribute__((ext_vector_type(8)));
typedef float f32x4 __attribute__((ext_vector_type(4)));
typedef float f32x2 __attribute__((ext_vector_type(2)));

__device__ __forceinline__ unsigned short f2bf(float f) {
  return __builtin_bit_cast(unsigned short, (__bf16)f);   // RNE; pairs fuse to v_cvt_pk_bf16_f32
}
__device__ __forceinline__ unsigned int pk2(float a, float b) {
  return (unsigned int)f2bf(a) | ((unsigned int)f2bf(b) << 16);
}
__device__ __forceinline__ uint4 pk8(float4 a, float4 b) {
  return make_uint4(pk2(a.x,a.y), pk2(a.z,a.w), pk2(b.x,b.y), pk2(b.z,b.w));
}
// fast GELU: x * sigmoid(1.5957691(x + 0.044715 x^3)); |err| <= ~1e-3 vs exact erf form
__device__ __forceinline__ float gelu_f(float x) {
  float x2 = x * x;
  float p  = __builtin_fmaf(0.044715f * x2, x, x);
  float e  = __expf(-1.5957691216057308f * p);
  return x * __builtin_amdgcn_rcpf(1.0f + e);
}

typedef const __attribute__((address_space(1))) void GV;
typedef __attribute__((address_space(3))) void LV;
__device__ __forceinline__ void gload16(const void* g, void* l) {
  __builtin_amdgcn_global_load_lds((GV*)g, (LV*)l, 16, 0, 0);
}

// ---------------- ws layout (ushort elements) ----------------
#define OFF_EW1 0          // [10 kc][4 kq][256 col][8 j] = 81920  (folded)
#define OFF_EW2 81920      // [8 kc][4 kq][128 col][8 j]  = 32768
#define OFF_NW1 114688     // [8 kc][4 kq][256 col][8 j]  = 65536
#define OFF_NW2 180224     // [8 kc][4 kq][128 col][8 j]  = 32768
#define PREP_TOT 212992

__global__ __launch_bounds__(256) void prep_weights(
    const float* __restrict__ eW1, const float* __restrict__ eW2,
    const float* __restrict__ nW1, const float* __restrict__ nW2,
    unsigned short* __restrict__ ws)
{
  int i = blockIdx.x * 256 + threadIdx.x;
  if (i < OFF_EW2) {                       // folded eW1 -> [kc][kq][col][8]
    int kc = i >> 13, rem = i & 8191;
    int kq = rem >> 11, col = (rem >> 3) & 255, j = i & 7;
    int k = kc * 32 + kq * 8 + j;          // 0..319 in folded A-space
    float v;
    if (k < 128)       v = eW1[k * EH + col] + eW1[(k + 256) * EH + col];
    else if (k < 256)  v = eW1[k * EH + col] - eW1[(k + 128) * EH + col];
    else               v = eW1[(k + 130) * EH + col];      // ef rows 386..449
    ws[i] = f2bf(v);
  } else if (i < OFF_NW1) {                // eW2 -> [kc][kq][col][8]
    int j0 = i - OFF_EW2;
    int kc = j0 >> 12, rem = j0 & 4095;
    int kq = rem >> 10, col = (rem >> 3) & 127, j = j0 & 7;
    int k = kc * 32 + kq * 8 + j;
    ws[i] = f2bf(eW2[k * EO + col]);
  } else if (i < OFF_NW2) {                // nW1 -> [kc][kq][col][8]
    int j0 = i - OFF_NW1;
    int kc = j0 >> 13, rem = j0 & 8191;
    int kq = rem >> 11, col = (rem >> 3) & 255, j = j0 & 7;
    int k = kc * 32 + kq * 8 + j;
    ws[i] = f2bf(nW1[k * NH + col]);
  } else if (i < PREP_TOT) {               // nW2 -> [kc][kq][col][8]
    int j0 = i - OFF_NW2;
    int kc = j0 >> 12, rem = j0 & 4095;
    int kq = rem >> 10, col = (rem >> 3) & 127, j = j0 & 7;
    int k = kc * 32 + kq * 8 + j;
    ws[i] = f2bf(nW2[k * NO + col]);
  }
}

// ---------------- edge kernel: 64 edges/block, 8 waves ----------------
__global__ __launch_bounds__(512, 4) void edge_kernel(
    const float* __restrict__ nf, const float* __restrict__ ef,
    const int* __restrict__ ei,
    const float* __restrict__ eW1, const float* __restrict__ eb1,
    const float* __restrict__ eg1, const float* __restrict__ ebt1,
    const float* __restrict__ eb2, const float* __restrict__ eg2,
    const float* __restrict__ ebt2,
    const unsigned short* __restrict__ W1e,   // [10][4][256][8]
    const unsigned short* __restrict__ W2e,   // [8][4][128][8]
    float* __restrict__ out)
{
  // A: 64 rows x 320 bf16 (640 B/row), XOR-swizzled in 16B units within 128B windows.
  // Reused after GEMM1 as h[64][HSTR] (33792 B <= 40960 B).
  __shared__ __align__(16) unsigned short Ab[ME_TILE * AK];  // 40960 B
  __shared__ __align__(16) char Bbc[32768];                  // double-buffered weight staging
  __shared__ float radL[ME_TILE], distL[ME_TILE];
  __shared__ int   tgtL[ME_TILE];
  __shared__ float sumL[2][ME_TILE], sqL[2][ME_TILE];

  const int tid  = threadIdx.x;
  const int lane = tid & 63;
  const int wave = tid >> 6;            // 0..7
  const int e0   = blockIdx.x * ME_TILE;

  // ---- prefetch GEMM1 chunk 0 into Bbc[0:16384] (async, drains at first barrier) ----
  {
    const char* g = (const char*)W1e + wave * 2048 + lane * 16;
    char* l = Bbc + wave * 2048;
    gload16(g, l);
    gload16(g + 1024, l + 1024);
  }

  // ---- build A = [src|tgt|ef] (bf16, swizzled, b128 writes); rad in fp32 ----
  {
    const int r = tid >> 3, g = tid & 7;   // 8 threads per edge
    const int e = e0 + r;
    const int si = ei[e];
    const int ti = ei[N_EDGES + e];
    const float4* sp = (const float4*)(nf + (size_t)si * DD) + g * 4;
    const float4* tp = (const float4*)(nf + (size_t)ti * DD) + g * 4;
    float4 s0 = sp[0], s1 = sp[1], s2 = sp[2], s3 = sp[3];
    float4 t0 = tp[0], t1 = tp[1], t2 = tp[2], t3 = tp[3];
    float d0x=s0.x-t0.x, d0y=s0.y-t0.y, d0z=s0.z-t0.z, d0w=s0.w-t0.w;
    float d1x=s1.x-t1.x, d1y=s1.y-t1.y, d1z=s1.z-t1.z, d1w=s1.w-t1.w;
    float d2x=s2.x-t2.x, d2y=s2.y-t2.y, d2z=s2.z-t2.z, d2w=s2.w-t2.w;
    float d3x=s3.x-t3.x, d3y=s3.y-t3.y, d3z=s3.z-t3.z, d3w=s3.w-t3.w;
    float rad = d0x*d0x + d0y*d0y + d0z*d0z + d0w*d0w
              + d1x*d1x + d1y*d1y + d1z*d1z + d1w*d1w
              + d2x*d2x + d2y*d2y + d2z*d2z + d2w*d2w
              + d3x*d3x + d3y*d3y + d3z*d3z + d3w*d3w;
    const int rx = r & 7;
    char* Arow = (char*)Ab + r * (AK * 2);
    // 16B unit u -> phys (u&~7) | ((u&7)^rx)
    #define STA(u, v) *(uint4*)(Arow + (((u) & ~7) | (((u) & 7) ^ rx)) * 16) = (v)
    STA(2*g,      pk8(s0, s1));  STA(2*g + 1,  pk8(s2, s3));   // units 0..15
    STA(16 + 2*g, pk8(t0, t1));  STA(17 + 2*g, pk8(t2, t3));   // units 16..31
    const float4* ep = (const float4*)(ef + (size_t)e * EDF) + g * 2;
    float4 u0 = ep[0], u1 = ep[1];
    STA(32 + g,   pk8(u0, u1));                                 // units 32..39
    #undef STA
    rad += __shfl_xor(rad, 1);
    rad += __shfl_xor(rad, 2);
    rad += __shfl_xor(rad, 4);
    if (g == 0) {
      radL[r]  = rad;
      distL[r] = sqrtf(rad + 1e-8f);
      tgtL[r]  = ti;
    }
  }

  const int wr = wave >> 1, wc = wave & 1;    // 4 row-groups x 2 col-groups
  const int r4 = lane >> 4, cl = lane & 15;
  const int arow = wr * 16 + cl;
  const int rx = arow & 7;
  const char* Abase = (const char*)Ab + arow * (AK * 2);

  f32x4 acc[8];
#pragma unroll
  for (int t = 0; t < 8; ++t) { f32x4 z = {0.f,0.f,0.f,0.f}; acc[t] = z; }

  __syncthreads();   // A ready; chunk 0 staged

  // ---- GEMM1: [64,320] x [320,256]; dbuf staging; wave tile 16 x 128 ----
#pragma unroll
  for (int kc = 0; kc < NKC1; ++kc) {
    if (kc + 1 < NKC1) {               // stage next chunk into the other buffer
      const char* g = (const char*)W1e + (size_t)(kc + 1) * 16384 + wave * 2048 + lane * 16;
      char* l = Bbc + ((kc + 1) & 1) * 16384 + wave * 2048;
      gload16(g, l);
      gload16(g + 1024, l + 1024);
    }
    const char* Bcur = Bbc + (kc & 1) * 16384;
    int u = kc * 4 + r4;
    int pu = (u & ~7) | ((u & 7) ^ rx);
    s16x8 af = *(const s16x8*)(Abase + pu * 16);
#pragma unroll
    for (int t = 0; t < 8; ++t) {
      s16x8 bf = *(const s16x8*)(Bcur + r4 * 4096 + (wc * 128 + t * 16 + cl) * 16);
      acc[t] = __builtin_amdgcn_mfma_f32_16x16x32_bf16(af, bf, acc[t], 0, 0, 0);
    }
    __syncthreads();   // drains stage; guards buffer reuse
  }

  // ---- epilogue 1: bias + fp32 rad/dist correction + LN + GELU -> h ----
  float eb1c[8], eg1c[8], ebt1c[8], w4c[8], w5c[8];
#pragma unroll
  for (int t = 0; t < 8; ++t) {
    int c = wc * 128 + t * 16 + cl;
    eb1c[t] = eb1[c]; eg1c[t] = eg1[c]; ebt1c[t] = ebt1[c];
    w4c[t] = eW1[384 * EH + c]; w5c[t] = eW1[385 * EH + c];
  }
  float xs[8][4], mean1[4], inv1[4];
#pragma unroll
  for (int rr = 0; rr < 4; ++rr) {
    int row = wr * 16 + r4 * 4 + rr;
    float rad = radL[row], dst = distL[row];
    float ps = 0.f, pq = 0.f;
#pragma unroll
    for (int t = 0; t < 8; ++t) {
      float x = acc[t][rr] + eb1c[t] + rad * w4c[t] + dst * w5c[t];
      xs[t][rr] = x; ps += x; pq += x * x;
    }
    ps += __shfl_xor(ps, 1); pq += __shfl_xor(pq, 1);
    ps += __shfl_xor(ps, 2); pq += __shfl_xor(pq, 2);
    ps += __shfl_xor(ps, 4); pq += __shfl_xor(pq, 4);
    ps += __shfl_xor(ps, 8); pq += __shfl_xor(pq, 8);
    if (cl == 0) { sumL[wc][row] = ps; sqL[wc][row] = pq; }
  }
  __syncthreads();   // sums visible; all GEMM1 Bb reads complete

  // prefetch GEMM2 chunk 0 into Bbc[0:8192] (latency hidden under LN/GELU below)
  {
    const char* g = (const char*)W2e + wave * 1024 + lane * 16;
    gload16(g, Bbc + wave * 1024);
  }

  unsigned short* hb = (unsigned short*)Ab;   // h[64][HSTR] overlays A
#pragma unroll
  for (int rr = 0; rr < 4; ++rr) {
    int row = wr * 16 + r4 * 4 + rr;
    float s = sumL[0][row] + sumL[1][row];
    float q = sqL[0][row] + sqL[1][row];
    float m = s * (1.f / 256.f);
    float v = q * (1.f / 256.f) - m * m;
    mean1[rr] = m; inv1[rr] = rsqrtf(v + LN_EPS);
  }
#pragma unroll
  for (int t = 0; t < 8; ++t) {
#pragma unroll
    for (int rr = 0; rr < 4; ++rr) {
      int row = wr * 16 + r4 * 4 + rr;
      int c = wc * 128 + t * 16 + cl;
      float y = (xs[t][rr] - mean1[rr]) * inv1[rr] * eg1c[t] + ebt1c[t];
      hb[row * HSTR + c] = f2bf(gelu_f(y));
    }
  }
  __syncthreads();   // h ready + GEMM2 chunk 0 staged

  // ---- GEMM2: [64,256] x [256,128]; dbuf (8 KB halves); wave tile 16 x 64 ----
  f32x4 a2[4];
#pragma unroll
  for (int t = 0; t < 4; ++t) { f32x4 z = {0.f,0.f,0.f,0.f}; a2[t] = z; }

#pragma unroll
  for (int kc = 0; kc < NKC2; ++kc) {
    if (kc + 1 < NKC2) {
      const char* g = (const char*)W2e + (size_t)(kc + 1) * 8192 + wave * 1024 + lane * 16;
      gload16(g, Bbc + ((kc + 1) & 1) * 8192 + wave * 1024);
    }
    const char* Bcur = Bbc + (kc & 1) * 8192;
    s16x8 af = *(const s16x8*)((const char*)hb + arow * (HSTR * 2) + kc * 64 + r4 * 16);
#pragma unroll
    for (int t = 0; t < 4; ++t) {
      s16x8 bf = *(const s16x8*)(Bcur + r4 * 2048 + (wc * 64 + t * 16 + cl) * 16);
      a2[t] = __builtin_amdgcn_mfma_f32_16x16x32_bf16(af, bf, a2[t], 0, 0, 0);
    }
    __syncthreads();
  }

  // ---- epilogue 2: bias + LN + GELU -> edge_out (packed nt) + atomic agg ----
  float eb2c[4], eg2c[4], ebt2c[4];
#pragma unroll
  for (int t = 0; t < 4; ++t) {
    int c = wc * 64 + t * 16 + cl;
    eb2c[t] = eb2[c]; eg2c[t] = eg2[c]; ebt2c[t] = ebt2[c];
  }
  float xs2[4][4], mean2[4], inv2[4];
#pragma unroll
  for (int rr = 0; rr < 4; ++rr) {
    int row = wr * 16 + r4 * 4 + rr;
    float ps = 0.f, pq = 0.f;
#pragma unroll
    for (int t = 0; t < 4; ++t) {
      float x = a2[t][rr] + eb2c[t];
      xs2[t][rr] = x; ps += x; pq += x * x;
    }
    ps += __shfl_xor(ps, 1); pq += __shfl_xor(pq, 1);
    ps += __shfl_xor(ps, 2); pq += __shfl_xor(pq, 2);
    ps += __shfl_xor(ps, 4); pq += __shfl_xor(pq, 4);
    ps += __shfl_xor(ps, 8); pq += __shfl_xor(pq, 8);
    if (cl == 0) { sumL[wc][row] = ps; sqL[wc][row] = pq; }
  }
  __syncthreads();
#pragma unroll
  for (int rr = 0; rr < 4; ++rr) {
    int row = wr * 16 + r4 * 4 + rr;
    float s = sumL[0][row] + sumL[1][row];
    float q = sqL[0][row] + sqL[1][row];
    float m = s * (1.f / 128.f);
    float v = q * (1.f / 128.f) - m * m;
    mean2[rr] = m; inv2[rr] = rsqrtf(v + LN_EPS);
  }
#pragma unroll
  for (int t = 0; t < 4; ++t) {
#pragma unroll
    for (int rr = 0; rr < 4; ++rr) {
      int row = wr * 16 + r4 * 4 + rr;
      int c = wc * 64 + t * 16 + cl;
      float y = (xs2[t][rr] - mean2[rr]) * inv2[rr] * eg2c[t] + ebt2c[t];
      float val = gelu_f(y);
      float pv  = __shfl_xor(val, 1);         // partner column value
      int e = e0 + row;
      atomicAdd(out + (size_t)tgtL[row] * NO + c, val);
      if ((lane & 1) == 0) {                  // even cl: pack 2 adjacent cols, 8B nt store
        f32x2 v2; v2[0] = val; v2[1] = pv;
        __builtin_nontemporal_store(v2, (f32x2*)(out + NODE_OUT_SZ + (size_t)e * EO + c));
      }
    }
  }
}

// ---------------- node kernel: 32 nodes/block, 4 waves, same structure ----------------
__global__ __launch_bounds__(256, 4) void node_kernel(
    const float* __restrict__ nf,
    const float* __restrict__ nb1, const float* __restrict__ ng1, const float* __restrict__ nbt1,
    const float* __restrict__ nb2, const float* __restrict__ ng2, const float* __restrict__ nbt2,
    const unsigned short* __restrict__ W1n,   // [8][4][256][8]
    const unsigned short* __restrict__ W2n,   // [8][4][128][8]
    float* __restrict__ out)                  // reads agg rows, overwrites with node_out
{
  // A: 32 rows x 256 bf16 (512 B/row), swizzled; reused as h (same swizzled layout).
  __shared__ __align__(16) unsigned short Ab[32 * 256];    // 16384 B
  __shared__ __align__(16) char Bbc[32768];
  __shared__ float sumL[2][32], sqL[2][32];

  const int tid  = threadIdx.x;
  const int lane = tid & 63;
  const int wave = tid >> 6;            // 0..3
  const int n0   = blockIdx.x * 32;

  // prefetch GEMM1 chunk 0 (16 KB, 4 rounds of 4 KB)
  {
    const char* g = (const char*)W1n + tid * 16;
    char* l = Bbc + wave * 1024;
#pragma unroll
    for (int s = 0; s < 4; ++s) gload16(g + s * 4096, l + s * 4096);
  }

  // ---- build A = [nf | agg] (swizzled b128 writes) ----
  {
    const int r = tid >> 3, g = tid & 7;
    const int node = n0 + r;            // reads beyond N_NODES stay in-bounds of d_out
    const float4* xp = (const float4*)(nf  + (size_t)node * DD) + g * 4;
    const float4* ap = (const float4*)(out + (size_t)node * NO) + g * 4;
    float4 x0 = xp[0], x1 = xp[1], x2 = xp[2], x3 = xp[3];
    float4 a0 = ap[0], a1 = ap[1], a2v = ap[2], a3 = ap[3];
    const int rx = r & 7;
    char* Arow = (char*)Ab + r * 512;
    #define STN(u, v) *(uint4*)(Arow + (((u) & ~7) | (((u) & 7) ^ rx)) * 16) = (v)
    STN(2*g,      pk8(x0, x1));  STN(2*g + 1,  pk8(x2, x3));   // units 0..15 (nf)
    STN(16 + 2*g, pk8(a0, a1));  STN(17 + 2*g, pk8(a2v, a3));  // units 16..31 (agg)
    #undef STN
  }

  const int wr = wave >> 1, wc = wave & 1;    // 2 row-groups x 2 col-groups
  const int r4 = lane >> 4, cl = lane & 15;
  const int arow = wr * 16 + cl;
  const int rx = arow & 7;
  const char* Abase = (const char*)Ab + arow * 512;

  f32x4 acc[8];
#pragma unroll
  for (int t = 0; t < 8; ++t) { f32x4 z = {0.f,0.f,0.f,0.f}; acc[t] = z; }

  __syncthreads();

  // ---- GEMM1: [32,256] x [256,256]; dbuf; wave tile 16 x 128 ----
#pragma unroll
  for (int kc = 0; kc < 8; ++kc) {
    if (kc + 1 < 8) {
      const char* g = (const char*)W1n + (size_t)(kc + 1) * 16384 + tid * 16;
      char* l = Bbc + ((kc + 1) & 1) * 16384 + wave * 1024;
#pragma unroll
      for (int s = 0; s < 4; ++s) gload16(g + s * 4096, l + s * 4096);
    }
    const char* Bcur = Bbc + (kc & 1) * 16384;
    int u = kc * 4 + r4;
    int pu = (u & ~7) | ((u & 7) ^ rx);
    s16x8 af = *(const s16x8*)(Abase + pu * 16);
#pragma unroll
    for (int t = 0; t < 8; ++t) {
      s16x8 bf = *(const s16x8*)(Bcur + r4 * 4096 + (wc * 128 + t * 16 + cl) * 16);
      acc[t] = __builtin_amdgcn_mfma_f32_16x16x32_bf16(af, bf, acc[t], 0, 0, 0);
    }
    __syncthreads();
  }

  // ---- epilogue 1: bias + LN + GELU -> h (swizzled, overlays A) ----
  float b1c[8], g1c[8], bt1c[8];
#pragma unroll
  for (int t = 0; t < 8; ++t) {
    int c = wc * 128 + t * 16 + cl;
    b1c[t] = nb1[c]; g1c[t] = ng1[c]; bt1c[t] = nbt1[c];
  }
  float xs[8][4], mean1[4], inv1[4];
#pragma unroll
  for (int rr = 0; rr < 4; ++rr) {
    int row = wr * 16 + r4 * 4 + rr;
    float ps = 0.f, pq = 0.f;
#pragma unroll
    for (int t = 0; t < 8; ++t) {
      float x = acc[t][rr] + b1c[t];
      xs[t][rr] = x; ps += x; pq += x * x;
    }
    ps += __shfl_xor(ps, 1); pq += __shfl_xor(pq, 1);
    ps += __shfl_xor(ps, 2); pq += __shfl_xor(pq, 2);
    ps += __shfl_xor(ps, 4); pq += __shfl_xor(pq, 4);
    ps += __shfl_xor(ps, 8); pq += __shfl_xor(pq, 8);
    if (cl == 0) { sumL[wc][row] = ps; sqL[wc][row] = pq; }
  }
  __syncthreads();

  // prefetch GEMM2 chunk 0 (8 KB) into Bbc[0:8192]
  {
    const char* g = (const char*)W2n + tid * 16;
    char* l = Bbc + wave * 1024;
    gload16(g, l);
    gload16(g + 4096, l + 4096);
  }

#pragma unroll
  for (int rr = 0; rr < 4; ++rr) {
    int row = wr * 16 + r4 * 4 + rr;
    float s = sumL[0][row] + sumL[1][row];
    float q = sqL[0][row] + sqL[1][row];
    float m = s * (1.f / 256.f);
    float v = q * (1.f / 256.f) - m * m;
    mean1[rr] = m; inv1[rr] = rsqrtf(v + LN_EPS);
  }
  char* hB = (char*)Ab;
#pragma unroll
  for (int t = 0; t < 8; ++t) {
#pragma unroll
    for (int rr = 0; rr < 4; ++rr) {
      int row = wr * 16 + r4 * 4 + rr;
      int c = wc * 128 + t * 16 + cl;
      float y = (xs[t][rr] - mean1[rr]) * inv1[rr] * g1c[t] + bt1c[t];
      int un = c >> 3;
      int pun = (un & ~7) | ((un & 7) ^ (row & 7));
      *(unsigned short*)(hB + row * 512 + pun * 16 + (c & 7) * 2) = f2bf(gelu_f(y));
    }
  }
  __syncthreads();

  // ---- GEMM2: [32,256] x [256,128]; dbuf (8 KB halves); wave tile 16 x 64 ----
  f32x4 a2[4];
#pragma unroll
  for (int t = 0; t < 4; ++t) { f32x4 z = {0.f,0.f,0.f,0.f}; a2[t] = z; }

#pragma unroll
  for (int kc = 0; kc < 8; ++kc) {
    if (kc + 1 < 8) {
      const char* g = (const char*)W2n + (size_t)(kc + 1) * 8192 + tid * 16;
      char* l = Bbc + ((kc + 1) & 1) * 8192 + wave * 1024;
      gload16(g, l);
      gload16(g + 4096, l + 4096);
    }
    const char* Bcur = Bbc + (kc & 1) * 8192;
    int u = kc * 4 + r4;
    int pu = (u & ~7) | ((u & 7) ^ rx);
    s16x8 af = *(const s16x8*)(Abase + pu * 16);   // h, same swizzled layout as A
#pragma unroll
    for (int t = 0; t < 4; ++t) {
      s16x8 bf = *(const s16x8*)(Bcur + r4 * 2048 + (wc * 64 + t * 16 + cl) * 16);
      a2[t] = __builtin_amdgcn_mfma_f32_16x16x32_bf16(af, bf, a2[t], 0, 0, 0);
    }
    __syncthreads();
  }

  // ---- epilogue 2 -> node_out (packed stores) ----
  float b2c[4], g2c[4], bt2c[4];
#pragma unroll
  for (int t = 0; t < 4; ++t) {
    int c = wc * 64 + t * 16 + cl;
    b2c[t] = nb2[c]; g2c[t] = ng2[c]; bt2c[t] = nbt2[c];
  }
  float xs2[4][4], mean2[4], inv2[4];
#pragma unroll
  for (int rr = 0; rr < 4; ++rr) {
    int row = wr * 16 + r4 * 4 + rr;
    float ps = 0.f, pq = 0.f;
#pragma unroll
    for (int t = 0; t < 4; ++t) {
      float x = a2[t][rr] + b2c[t];
      xs2[t][rr] = x; ps += x; pq += x * x;
    }
    ps += __shfl_xor(ps, 1); pq += __shfl_xor(pq, 1);
    ps += __shfl_xor(ps, 2); pq += __shfl_xor(pq, 2);
    ps += __shfl_xor(ps, 4); pq += __shfl_xor(pq, 4);
    ps += __shfl_xor(ps, 8); pq += __shfl_xor(pq, 8);
    if (cl == 0) { sumL[wc][row] = ps; sqL[wc][row] = pq; }
  }
  __syncthreads();
#pragma unroll
  for (int rr = 0; rr < 4; ++rr) {
    int row = wr * 16 + r4 * 4 + rr;
    float s = sumL[0][row] + sumL[1][row];
    float q = sqL[0][row] + sqL[1][row];
    float m = s * (1.f / 128.f);
    float v = q * (1.f / 128.f) - m * m;
    mean2[rr] = m; inv2[rr] = rsqrtf(v + LN_EPS);
  }
#pragma unroll
  for (int t = 0; t < 4; ++t) {
#pragma unroll
    for (int rr = 0; rr < 4; ++rr) {
      int row = wr * 16 + r4 * 4 + rr;
      int node = n0 + row;
      int c = wc * 64 + t * 16 + cl;
      float y = (xs2[t][rr] - mean2[rr]) * inv2[rr] * g2c[t] + bt2c[t];
      float val = gelu_f(y);
      float pv  = __shfl_xor(val, 1);
      if (((lane & 1) == 0) && node < N_NODES) {
        f32x2 v2; v2[0] = val; v2[1] = pv;
        *(f32x2*)(out + (size_t)node * NO + c) = v2;
      }
    }
  }
}

// ---------------- launch ----------------
extern "C" void kernel_launch(void* const* d_in, const int* in_sizes, int n_in,
                              void* d_out, int out_size, void* d_ws, size_t ws_size,
                              hipStream_t stream) {
  const float* nf   = (const float*)d_in[0];
  const float* ef   = (const float*)d_in[1];
  const int*   ei   = (const int*)d_in[2];
  const float* eW1  = (const float*)d_in[3];
  const float* eb1  = (const float*)d_in[4];
  const float* eg1  = (const float*)d_in[5];
  const float* ebt1 = (const float*)d_in[6];
  const float* eW2  = (const float*)d_in[7];
  const float* eb2  = (const float*)d_in[8];
  const float* eg2  = (const float*)d_in[9];
  const float* ebt2 = (const float*)d_in[10];
  const float* nW1  = (const float*)d_in[11];
  const float* nb1  = (const float*)d_in[12];
  const float* ng1  = (const float*)d_in[13];
  const float* nbt1 = (const float*)d_in[14];
  const float* nW2  = (const float*)d_in[15];
  const float* nb2  = (const float*)d_in[16];
  const float* ng2  = (const float*)d_in[17];
  const float* nbt2 = (const float*)d_in[18];
  float* out = (float*)d_out;
  unsigned short* ws = (unsigned short*)d_ws;
  (void)in_sizes; (void)n_in; (void)out_size; (void)ws_size;

  (void)hipMemsetAsync(d_out, 0, (size_t)NODE_OUT_SZ * sizeof(float), stream);

  prep_weights<<<PREP_TOT / 256, 256, 0, stream>>>(eW1, eW2, nW1, nW2, ws);

  edge_kernel<<<N_EDGES / ME_TILE, 512, 0, stream>>>(
      nf, ef, ei, eW1, eb1, eg1, ebt1, eb2, eg2, ebt2,
      ws + OFF_EW1, ws + OFF_EW2, out);

  node_kernel<<<(N_NODES + 31) / 32, 256, 0, stream>>>(
      nf, nb1, ng1, nbt1, nb2, ng2, nbt2,
      ws + OFF_NW1, ws + OFF_NW2, out);
}